// Round 1
// baseline (364.268 us; speedup 1.0000x reference)
//
#include <hip/hip_runtime.h>
#include <hip/hip_bf16.h>
#include <math.h>

// ============================================================================
// SelfAttention B=4 S=4096 D=512, fp32 in/out, bf16 MFMA internally.
//
// Pipeline (all on `stream`):
//   1. prep_x:  X fp32 -> Xb bf16                      [16384,512]
//   2. prep_w:  Wq/Wk/Wv fp32 [in][out] -> Wt bf16 [g][out][in] (transposed)
//   3. gemm_bt<BIAS>   : Q  = Xb @ Wt_q^T + bq   (bf16, row-major [16384,512])
//      gemm_bt<BIAS>   : K  = Xb @ Wt_k^T + bk
//      gemm_bt<BIAS_T> : Vt = (Xb @ Wt_v^T + bv)^T  -> [b][512][4096]
//   4. memset rowsum = 0
//      gemm_bt<EXP>    : E = exp(scale * Q K^T) bf16 [b][4096][4096],
//                        rowsum[b][q] += partial row sums (atomic)
//   5. gemm_bt<DIV>    : out = (E @ Vt^T) / rowsum    (fp32)
//
// Softmax needs no max-subtraction: |score| <= |q||k|/sqrt(512) ~ 7.5, exp is
// safe in fp32; softmax is shift-invariant so result matches reference.
//
// GEMM: 128x128 block tile, BK=64, 4 waves (2x2), each wave 64x64 via 4x4
// mfma_f32_16x16x32_bf16. LDS tiles padded 64->72 cols (2-way bank alias =
// free per m136). Register-staged LDS this round (global_load_lds next).
// ============================================================================

typedef __bf16 bfx8 __attribute__((ext_vector_type(8)));
typedef __bf16 bfx4 __attribute__((ext_vector_type(4)));
typedef float  fx4  __attribute__((ext_vector_type(4)));

#define HID   512
#define NBATCH 4
#define SEQ   4096
#define MROWS (NBATCH * SEQ)

constexpr int MODE_BIAS   = 0;  // C bf16 row-major, += bias[n]
constexpr int MODE_BIAS_T = 1;  // C bf16 transposed per-batch, += bias[n]
constexpr int MODE_EXP    = 2;  // C bf16 = exp(scale*acc), atomic rowsum
constexpr int MODE_DIV    = 3;  // C fp32 = acc / rowsum[m]

// ---------------------------------------------------------------------------
__global__ void prep_x_kernel(const float* __restrict__ X, __bf16* __restrict__ Xb) {
  int i = (blockIdx.x * 256 + threadIdx.x) * 4;
  const float4 v = *(const float4*)(X + i);
  bfx4 o;
  o[0] = (__bf16)v.x; o[1] = (__bf16)v.y; o[2] = (__bf16)v.z; o[3] = (__bf16)v.w;
  *(bfx4*)(Xb + i) = o;
}

__global__ void prep_w_kernel(const float* __restrict__ Wq, const float* __restrict__ Wk,
                              const float* __restrict__ Wv, __bf16* __restrict__ Wt) {
  int id  = blockIdx.x * 256 + threadIdx.x;   // 0 .. 3*512*512-1
  int g   = id >> 18;
  int rem = id & ((1 << 18) - 1);
  int i   = rem >> 9;          // input dim (row of W)
  int o   = rem & 511;         // output dim (col of W) -- coalesced read
  const float* W = (g == 0) ? Wq : ((g == 1) ? Wk : Wv);
  Wt[(g << 18) + (o << 9) + i] = (__bf16)W[rem];
}

// ---------------------------------------------------------------------------
// C[M,N] = A[M,K] @ B[N,K]^T  (both row-major along K), + mode epilogue.
template <int MODE>
__global__ __launch_bounds__(256)
void gemm_bt(const __bf16* __restrict__ A, const __bf16* __restrict__ B,
             void* __restrict__ Cv, const float* __restrict__ bias,
             float* __restrict__ rowsum,
             int lda, int ldb, int ldc, int K_,
             long sA, long sB, long sC, int sR, float scale) {
  __shared__ __bf16 As[128 * 72];
  __shared__ __bf16 Bs[128 * 72];

  const int z = blockIdx.z;
  A += (long)z * sA;
  B += (long)z * sB;

  const int tid  = threadIdx.x;
  const int lane = tid & 63;
  const int w    = tid >> 6;
  const int wm   = w >> 1, wn = w & 1;
  const int lm   = lane & 15, lq = lane >> 4;

  const int row0 = blockIdx.y * 128;
  const int col0 = blockIdx.x * 128;

  const __bf16* Ag = A + (long)row0 * lda;
  const __bf16* Bg = B + (long)col0 * ldb;

  fx4 acc[4][4] = {};

  for (int kt = 0; kt < K_; kt += 64) {
    bfx8 av[4], bv[4];
#pragma unroll
    for (int it = 0; it < 4; ++it) {
      int id = it * 256 + tid;
      int r = id >> 3, c = (id & 7) << 3;
      av[it] = *(const bfx8*)(Ag + (long)r * lda + kt + c);
      bv[it] = *(const bfx8*)(Bg + (long)r * ldb + kt + c);
    }
    __syncthreads();  // previous compute done reading LDS
#pragma unroll
    for (int it = 0; it < 4; ++it) {
      int id = it * 256 + tid;
      int r = id >> 3, c = (id & 7) << 3;
      *(bfx8*)(As + r * 72 + c) = av[it];
      *(bfx8*)(Bs + r * 72 + c) = bv[it];
    }
    __syncthreads();
#pragma unroll
    for (int kk = 0; kk < 2; ++kk) {
      bfx8 af[4], bfr[4];
#pragma unroll
      for (int t = 0; t < 4; ++t) {
        af[t]  = *(const bfx8*)(As + (wm * 64 + t * 16 + lm) * 72 + kk * 32 + lq * 8);
        bfr[t] = *(const bfx8*)(Bs + (wn * 64 + t * 16 + lm) * 72 + kk * 32 + lq * 8);
      }
#pragma unroll
      for (int mt = 0; mt < 4; ++mt)
#pragma unroll
        for (int nt = 0; nt < 4; ++nt)
          acc[mt][nt] = __builtin_amdgcn_mfma_f32_16x16x32_bf16(af[mt], bfr[nt],
                                                                acc[mt][nt], 0, 0, 0);
    }
  }

  // ---- epilogue ----  C/D layout: col = lane&15, row = (lane>>4)*4 + i
  const int gr0 = row0 + wm * 64;  // + mt*16 + lq*4 + i
  const int gc0 = col0 + wn * 64;  // + nt*16 + lm

  if constexpr (MODE == MODE_BIAS || MODE == MODE_BIAS_T) {
    float bvv[4];
#pragma unroll
    for (int nt = 0; nt < 4; ++nt) bvv[nt] = bias[gc0 + nt * 16 + lm];

    if constexpr (MODE == MODE_BIAS) {
      __bf16* C = (__bf16*)Cv;
#pragma unroll
      for (int mt = 0; mt < 4; ++mt)
#pragma unroll
        for (int nt = 0; nt < 4; ++nt)
#pragma unroll
          for (int i = 0; i < 4; ++i) {
            int r = gr0 + mt * 16 + lq * 4 + i;
            int c = gc0 + nt * 16 + lm;
            C[(long)r * ldc + c] = (__bf16)(acc[mt][nt][i] + bvv[nt]);
          }
    } else {  // transposed store: Vt[b][n][s], 4 consecutive seq -> 8B store
      __bf16* C = (__bf16*)Cv;
#pragma unroll
      for (int mt = 0; mt < 4; ++mt)
#pragma unroll
        for (int nt = 0; nt < 4; ++nt) {
          int c  = gc0 + nt * 16 + lm;          // output dim
          int rb = gr0 + mt * 16 + lq * 4;      // global row (b*4096+s)
          int b  = rb >> 12;
          int s  = rb & 4095;
          bfx4 pk;
#pragma unroll
          for (int i = 0; i < 4; ++i) pk[i] = (__bf16)(acc[mt][nt][i] + bvv[nt]);
          *(bfx4*)(C + ((long)b * HID + c) * SEQ + s) = pk;
        }
    }
  } else if constexpr (MODE == MODE_EXP) {
    __bf16* C = ((__bf16*)Cv) + (long)z * sC;
    float* rsump = rowsum + (long)z * sR;
#pragma unroll
    for (int mt = 0; mt < 4; ++mt)
#pragma unroll
      for (int i = 0; i < 4; ++i) {
        int r = gr0 + mt * 16 + lq * 4 + i;
        float rs = 0.f;
#pragma unroll
        for (int nt = 0; nt < 4; ++nt) {
          float e = __expf(acc[mt][nt][i] * scale);
          C[(long)r * ldc + gc0 + nt * 16 + lm] = (__bf16)e;
          rs += e;
        }
        rs += __shfl_xor(rs, 1);
        rs += __shfl_xor(rs, 2);
        rs += __shfl_xor(rs, 4);
        rs += __shfl_xor(rs, 8);
        if (lm == 0) atomicAdd(&rsump[r], rs);
      }
  } else {  // MODE_DIV
    float* C = ((float*)Cv) + (long)z * sC;
    const float* rsump = rowsum + (long)z * sR;
#pragma unroll
    for (int mt = 0; mt < 4; ++mt)
#pragma unroll
      for (int i = 0; i < 4; ++i) {
        int r = gr0 + mt * 16 + lq * 4 + i;
        float inv = 1.f / rsump[r];
#pragma unroll
        for (int nt = 0; nt < 4; ++nt)
          C[(long)r * ldc + gc0 + nt * 16 + lm] = acc[mt][nt][i] * inv;
      }
  }
}

// ---------------------------------------------------------------------------
extern "C" void kernel_launch(void* const* d_in, const int* in_sizes, int n_in,
                              void* d_out, int out_size, void* d_ws, size_t ws_size,
                              hipStream_t stream) {
  (void)in_sizes; (void)n_in; (void)out_size; (void)ws_size;
  const float* X  = (const float*)d_in[0];
  const float* Wq = (const float*)d_in[1];
  const float* bq = (const float*)d_in[2];
  const float* Wk = (const float*)d_in[3];
  const float* bk = (const float*)d_in[4];
  const float* Wv = (const float*)d_in[5];
  const float* bv = (const float*)d_in[6];
  float* out = (float*)d_out;

  // workspace layout (bf16 elements unless noted); total ~193.6 MB
  __bf16* Xb     = (__bf16*)d_ws;                 // 16384*512
  __bf16* Wt     = Xb + (long)MROWS * HID;        // 3*512*512, [g][out][in]
  __bf16* Q      = Wt + 3 * HID * HID;            // 16384*512
  __bf16* Kb     = Q + (long)MROWS * HID;         // 16384*512
  __bf16* Vt     = Kb + (long)MROWS * HID;        // [b][512][4096]
  float*  rowsum = (float*)(Vt + (long)MROWS * HID);  // 16384 fp32
  __bf16* E      = (__bf16*)(rowsum + MROWS);     // [b][4096][4096]

  const float scale = 0.04419417382415922f;  // 1/sqrt(512)

  prep_x_kernel<<<(MROWS * HID) / 1024, 256, 0, stream>>>(X, Xb);
  prep_w_kernel<<<(3 * HID * HID) / 256, 256, 0, stream>>>(Wq, Wk, Wv, Wt);

  // projections: M=16384, N=512, K=512
  gemm_bt<MODE_BIAS><<<dim3(4, 128, 1), 256, 0, stream>>>(
      Xb, Wt, Q, bq, nullptr, HID, HID, HID, HID, 0, 0, 0, 0, 0.f);
  gemm_bt<MODE_BIAS><<<dim3(4, 128, 1), 256, 0, stream>>>(
      Xb, Wt + HID * HID, Kb, bk, nullptr, HID, HID, HID, HID, 0, 0, 0, 0, 0.f);
  gemm_bt<MODE_BIAS_T><<<dim3(4, 128, 1), 256, 0, stream>>>(
      Xb, Wt + 2 * HID * HID, Vt, bv, nullptr, HID, HID, HID, HID, 0, 0, 0, 0, 0.f);

  (void)hipMemsetAsync(rowsum, 0, MROWS * sizeof(float), stream);

  // E = exp(scale * Q K^T): per batch M=N=4096, K=512
  gemm_bt<MODE_EXP><<<dim3(32, 32, NBATCH), 256, 0, stream>>>(
      Q, Kb, E, nullptr, rowsum, HID, HID, SEQ, HID,
      (long)SEQ * HID, (long)SEQ * HID, (long)SEQ * SEQ, SEQ, scale);

  // out = (E @ Vt^T) / rowsum: per batch M=4096, N=512, K=4096
  gemm_bt<MODE_DIV><<<dim3(4, 32, NBATCH), 256, 0, stream>>>(
      E, Vt, out, nullptr, rowsum, SEQ, SEQ, HID, SEQ,
      (long)SEQ * SEQ, (long)HID * SEQ, (long)SEQ * HID, SEQ, 0.f);
}

// Round 2
// 352.439 us; speedup vs baseline: 1.0336x; 1.0336x over previous
//
#include <hip/hip_runtime.h>
#include <hip/hip_bf16.h>
#include <math.h>

// ============================================================================
// SelfAttention B=4 S=4096 D=512, fp32 in/out, bf16 MFMA internally.
//
// R2: gemm_bt ported to the m97 structure — global_load_lds width=16 staging
// (no VGPR round-trip), unpadded 128x64 LDS tiles (global_load_lds writes
// wave-uniform base + lane*16B, so no padding allowed), XOR chunk swizzle
// (chunk ^= row&7) applied identically on the global-read mapping and the
// LDS fragment reads to kill ds_read_b128 bank conflicts while keeping
// global loads coalesced (row's 8 chunks permuted within one 128B segment).
//
// Pipeline (all on `stream`):
//   1. prep_x:  X fp32 -> Xb bf16                      [16384,512]
//   2. prep_w:  Wq/Wk/Wv fp32 [in][out] -> Wt bf16 [g][out][in] (transposed)
//   3. gemm_bt<BIAS>   : Q  = Xb @ Wt_q^T + bq   (bf16, row-major)
//      gemm_bt<BIAS>   : K  = Xb @ Wt_k^T + bk
//      gemm_bt<BIAS_T> : Vt = (Xb @ Wt_v^T + bv)^T  -> [b][512][4096]
//   4. memset rowsum; gemm_bt<EXP>: E = exp(scale*QK^T) bf16, rowsum atomics
//   5. gemm_bt<DIV>    : out = (E @ Vt^T) / rowsum    (fp32)
//
// Softmax needs no max-subtraction: |score| <= |q||k|/sqrt(512) ~ 7.5.
// ============================================================================

typedef __bf16 bfx8 __attribute__((ext_vector_type(8)));
typedef __bf16 bfx4 __attribute__((ext_vector_type(4)));
typedef float  fx4  __attribute__((ext_vector_type(4)));

#define HID   512
#define NBATCH 4
#define SEQ   4096
#define MROWS (NBATCH * SEQ)

constexpr int MODE_BIAS   = 0;  // C bf16 row-major, += bias[n]
constexpr int MODE_BIAS_T = 1;  // C bf16 transposed per-batch, += bias[n]
constexpr int MODE_EXP    = 2;  // C bf16 = exp(scale*acc), atomic rowsum
constexpr int MODE_DIV    = 3;  // C fp32 = acc / rowsum[m]

// ---------------------------------------------------------------------------
__device__ __forceinline__ void gload_lds16(const __bf16* gsrc, __bf16* ldst) {
  __builtin_amdgcn_global_load_lds(
      (const __attribute__((address_space(1))) unsigned int*)gsrc,
      (__attribute__((address_space(3))) unsigned int*)ldst,
      16, 0, 0);
}

// ---------------------------------------------------------------------------
__global__ void prep_x_kernel(const float* __restrict__ X, __bf16* __restrict__ Xb) {
  int i = (blockIdx.x * 256 + threadIdx.x) * 4;
  const float4 v = *(const float4*)(X + i);
  bfx4 o;
  o[0] = (__bf16)v.x; o[1] = (__bf16)v.y; o[2] = (__bf16)v.z; o[3] = (__bf16)v.w;
  *(bfx4*)(Xb + i) = o;
}

__global__ void prep_w_kernel(const float* __restrict__ Wq, const float* __restrict__ Wk,
                              const float* __restrict__ Wv, __bf16* __restrict__ Wt) {
  int id  = blockIdx.x * 256 + threadIdx.x;   // 0 .. 3*512*512-1
  int g   = id >> 18;
  int rem = id & ((1 << 18) - 1);
  int i   = rem >> 9;          // input dim (row of W)
  int o   = rem & 511;         // output dim (col of W) -- coalesced read
  const float* W = (g == 0) ? Wq : ((g == 1) ? Wk : Wv);
  Wt[(g << 18) + (o << 9) + i] = (__bf16)W[rem];
}

// ---------------------------------------------------------------------------
// C[M,N] = A[M,K] @ B[N,K]^T  (both row-major along K), + mode epilogue.
// 128x128 block tile, BK=64, 4 waves (2x2), each wave 64x64 via 4x4
// mfma_f32_16x16x32_bf16. LDS per tile: [128 rows][8 chunks of 8 bf16],
// physical chunk = logical chunk ^ (row&7).
template <int MODE>
__global__ __launch_bounds__(256)
void gemm_bt(const __bf16* __restrict__ A, const __bf16* __restrict__ B,
             void* __restrict__ Cv, const float* __restrict__ bias,
             float* __restrict__ rowsum,
             int lda, int ldb, int ldc, int K_,
             long sA, long sB, long sC, int sR, float scale) {
  __shared__ __bf16 As[128 * 64];
  __shared__ __bf16 Bs[128 * 64];

  const int z = blockIdx.z;
  A += (long)z * sA;
  B += (long)z * sB;

  const int tid  = threadIdx.x;
  const int lane = tid & 63;
  const int w    = tid >> 6;
  const int wm   = w >> 1, wn = w & 1;
  const int lm   = lane & 15, lq = lane >> 4;

  const int row0 = blockIdx.y * 128;
  const int col0 = blockIdx.x * 128;

  const __bf16* Ag = A + (long)row0 * lda;
  const __bf16* Bg = B + (long)col0 * ldb;

  // staging slot (per it: slot s = it*256+tid): row, swizzled global chunk
  int srow[4], sgc[4];
#pragma unroll
  for (int it = 0; it < 4; ++it) {
    int s = it * 256 + tid;
    int r = s >> 3, c = s & 7;
    srow[it] = r;
    sgc[it]  = (c ^ (r & 7)) << 3;   // element offset within row
  }
  const int ldsbase = (w * 64) * 8;  // wave-uniform element offset (+ it*2048)

  fx4 acc[4][4] = {};

  for (int kt = 0; kt < K_; kt += 64) {
    __syncthreads();  // previous compute done reading LDS
#pragma unroll
    for (int it = 0; it < 4; ++it) {
      gload_lds16(Ag + (long)srow[it] * lda + kt + sgc[it], As + it * 2048 + ldsbase);
      gload_lds16(Bg + (long)srow[it] * ldb + kt + sgc[it], Bs + it * 2048 + ldsbase);
    }
    __syncthreads();  // drains vmcnt(0) + barrier
#pragma unroll
    for (int kk = 0; kk < 2; ++kk) {
      bfx8 af[4], bfr[4];
#pragma unroll
      for (int t = 0; t < 4; ++t) {
        int ra = wm * 64 + t * 16 + lm;
        int rb = wn * 64 + t * 16 + lm;
        af[t]  = *(const bfx8*)(As + ra * 64 + (((kk * 4 + lq) ^ (ra & 7)) << 3));
        bfr[t] = *(const bfx8*)(Bs + rb * 64 + (((kk * 4 + lq) ^ (rb & 7)) << 3));
      }
#pragma unroll
      for (int mt = 0; mt < 4; ++mt)
#pragma unroll
        for (int nt = 0; nt < 4; ++nt)
          acc[mt][nt] = __builtin_amdgcn_mfma_f32_16x16x32_bf16(af[mt], bfr[nt],
                                                                acc[mt][nt], 0, 0, 0);
    }
  }

  // ---- epilogue ----  C/D layout: col = lane&15, row = (lane>>4)*4 + i
  const int gr0 = row0 + wm * 64;  // + mt*16 + lq*4 + i
  const int gc0 = col0 + wn * 64;  // + nt*16 + lm

  if constexpr (MODE == MODE_BIAS || MODE == MODE_BIAS_T) {
    float bvv[4];
#pragma unroll
    for (int nt = 0; nt < 4; ++nt) bvv[nt] = bias[gc0 + nt * 16 + lm];

    if constexpr (MODE == MODE_BIAS) {
      __bf16* C = (__bf16*)Cv;
#pragma unroll
      for (int mt = 0; mt < 4; ++mt)
#pragma unroll
        for (int nt = 0; nt < 4; ++nt)
#pragma unroll
          for (int i = 0; i < 4; ++i) {
            int r = gr0 + mt * 16 + lq * 4 + i;
            int c = gc0 + nt * 16 + lm;
            C[(long)r * ldc + c] = (__bf16)(acc[mt][nt][i] + bvv[nt]);
          }
    } else {  // transposed store: Vt[b][n][s], 4 consecutive seq -> 8B store
      __bf16* C = (__bf16*)Cv;
#pragma unroll
      for (int mt = 0; mt < 4; ++mt)
#pragma unroll
        for (int nt = 0; nt < 4; ++nt) {
          int c  = gc0 + nt * 16 + lm;          // output dim
          int rb = gr0 + mt * 16 + lq * 4;      // global row (b*4096+s)
          int b  = rb >> 12;
          int s  = rb & 4095;
          bfx4 pk;
#pragma unroll
          for (int i = 0; i < 4; ++i) pk[i] = (__bf16)(acc[mt][nt][i] + bvv[nt]);
          *(bfx4*)(C + ((long)b * HID + c) * SEQ + s) = pk;
        }
    }
  } else if constexpr (MODE == MODE_EXP) {
    __bf16* C = ((__bf16*)Cv) + (long)z * sC;
    float* rsump = rowsum + (long)z * sR;
#pragma unroll
    for (int mt = 0; mt < 4; ++mt)
#pragma unroll
      for (int i = 0; i < 4; ++i) {
        int r = gr0 + mt * 16 + lq * 4 + i;
        float rs = 0.f;
#pragma unroll
        for (int nt = 0; nt < 4; ++nt) {
          float e = __expf(acc[mt][nt][i] * scale);
          C[(long)r * ldc + gc0 + nt * 16 + lm] = (__bf16)e;
          rs += e;
        }
        rs += __shfl_xor(rs, 1);
        rs += __shfl_xor(rs, 2);
        rs += __shfl_xor(rs, 4);
        rs += __shfl_xor(rs, 8);
        if (lm == 0) atomicAdd(&rsump[r], rs);
      }
  } else {  // MODE_DIV
    float* C = ((float*)Cv) + (long)z * sC;
    const float* rsump = rowsum + (long)z * sR;
#pragma unroll
    for (int mt = 0; mt < 4; ++mt)
#pragma unroll
      for (int i = 0; i < 4; ++i) {
        int r = gr0 + mt * 16 + lq * 4 + i;
        float inv = 1.f / rsump[r];
#pragma unroll
        for (int nt = 0; nt < 4; ++nt)
          C[(long)r * ldc + gc0 + nt * 16 + lm] = acc[mt][nt][i] * inv;
      }
  }
}

// ---------------------------------------------------------------------------
extern "C" void kernel_launch(void* const* d_in, const int* in_sizes, int n_in,
                              void* d_out, int out_size, void* d_ws, size_t ws_size,
                              hipStream_t stream) {
  (void)in_sizes; (void)n_in; (void)out_size; (void)ws_size;
  const float* X  = (const float*)d_in[0];
  const float* Wq = (const float*)d_in[1];
  const float* bq = (const float*)d_in[2];
  const float* Wk = (const float*)d_in[3];
  const float* bk = (const float*)d_in[4];
  const float* Wv = (const float*)d_in[5];
  const float* bv = (const float*)d_in[6];
  float* out = (float*)d_out;

  // workspace layout (bf16 elements unless noted); total ~193.6 MB
  __bf16* Xb     = (__bf16*)d_ws;                 // 16384*512
  __bf16* Wt     = Xb + (long)MROWS * HID;        // 3*512*512, [g][out][in]
  __bf16* Q      = Wt + 3 * HID * HID;            // 16384*512
  __bf16* Kb     = Q + (long)MROWS * HID;         // 16384*512
  __bf16* Vt     = Kb + (long)MROWS * HID;        // [b][512][4096]
  float*  rowsum = (float*)(Vt + (long)MROWS * HID);  // 16384 fp32
  __bf16* E      = (__bf16*)(rowsum + MROWS);     // [b][4096][4096]

  const float scale = 0.04419417382415922f;  // 1/sqrt(512)

  prep_x_kernel<<<(MROWS * HID) / 1024, 256, 0, stream>>>(X, Xb);
  prep_w_kernel<<<(3 * HID * HID) / 256, 256, 0, stream>>>(Wq, Wk, Wv, Wt);

  // projections: M=16384, N=512, K=512
  gemm_bt<MODE_BIAS><<<dim3(4, 128, 1), 256, 0, stream>>>(
      Xb, Wt, Q, bq, nullptr, HID, HID, HID, HID, 0, 0, 0, 0, 0.f);
  gemm_bt<MODE_BIAS><<<dim3(4, 128, 1), 256, 0, stream>>>(
      Xb, Wt + HID * HID, Kb, bk, nullptr, HID, HID, HID, HID, 0, 0, 0, 0, 0.f);
  gemm_bt<MODE_BIAS_T><<<dim3(4, 128, 1), 256, 0, stream>>>(
      Xb, Wt + 2 * HID * HID, Vt, bv, nullptr, HID, HID, HID, HID, 0, 0, 0, 0, 0.f);

  (void)hipMemsetAsync(rowsum, 0, MROWS * sizeof(float), stream);

  // E = exp(scale * Q K^T): per batch M=N=4096, K=512
  gemm_bt<MODE_EXP><<<dim3(32, 32, NBATCH), 256, 0, stream>>>(
      Q, Kb, E, nullptr, rowsum, HID, HID, SEQ, HID,
      (long)SEQ * HID, (long)SEQ * HID, (long)SEQ * SEQ, SEQ, scale);

  // out = (E @ Vt^T) / rowsum: per batch M=4096, N=512, K=4096
  gemm_bt<MODE_DIV><<<dim3(4, 32, NBATCH), 256, 0, stream>>>(
      E, Vt, out, nullptr, rowsum, SEQ, SEQ, HID, SEQ,
      (long)SEQ * SEQ, (long)HID * SEQ, (long)SEQ * HID, SEQ, 0.f);
}